// Round 1
// baseline (42.672 us; speedup 1.0000x reference)
//
#include <hip/hip_runtime.h>

// SoftDiceLoss: predictions [B=8, C=16, H=512, W=512] fp32, targets [B,H,W] int32.
// out[b] = -(1/C) * sum_c (2*overlap[b,c] + 1) / (i_sum[b,c] + count[b,c] + 1)
//
// Stage 1: 1024 blocks (128 per batch) x 256 threads; each thread handles
//   8 spatial positions (2 x float4) across all 16 channels, accumulating
//   48 per-class registers, then wave-shuffle + LDS block reduction ->
//   partial[block][48] in d_ws (deterministic, no float atomics).
// Stage 2: 8 blocks (one per batch) reduce the 128 partial rows and emit out[b].

constexpr int  C_CLS        = 16;
constexpr long HW           = 512L * 512L;   // 262144
constexpr int  BATCH        = 8;
constexpr int  BLOCKS_PER_B = 128;
constexpr int  THREADS      = 256;
constexpr int  ITERS        = 2;             // 2 x (256 threads x 4 floats) = 2048 pos/block
// 128 blocks * 2048 = 262144 = HW  (exact cover)

__global__ __launch_bounds__(THREADS)
void dice_partial_kernel(const float* __restrict__ pred,
                         const int*   __restrict__ tgt,
                         float*       __restrict__ partial) {
    const int g     = blockIdx.x;
    const int b     = g / BLOCKS_PER_B;
    const int chunk = g % BLOCKS_PER_B;
    const int tid   = threadIdx.x;

    float isum[C_CLS], ov[C_CLS], cnt[C_CLS];
#pragma unroll
    for (int c = 0; c < C_CLS; ++c) { isum[c] = 0.f; ov[c] = 0.f; cnt[c] = 0.f; }

    const float* pb = pred + (long)b * C_CLS * HW;
    const int*   tb = tgt  + (long)b * HW;

#pragma unroll
    for (int it = 0; it < ITERS; ++it) {
        const long pos = (long)chunk * 2048 + it * 1024 + tid * 4;
        const int4 t = *reinterpret_cast<const int4*>(tb + pos);
#pragma unroll
        for (int c = 0; c < C_CLS; ++c) {
            const float4 p = *reinterpret_cast<const float4*>(pb + (long)c * HW + pos);
            isum[c] += (p.x + p.y) + (p.z + p.w);
            ov[c]   += ((t.x == c) ? p.x : 0.f) + ((t.y == c) ? p.y : 0.f)
                     + ((t.z == c) ? p.z : 0.f) + ((t.w == c) ? p.w : 0.f);
            cnt[c]  += ((t.x == c) ? 1.f : 0.f) + ((t.y == c) ? 1.f : 0.f)
                     + ((t.z == c) ? 1.f : 0.f) + ((t.w == c) ? 1.f : 0.f);
        }
    }

    // wave64 tree reduce each of the 48 accumulators
    const int lane = tid & 63;
    const int wv   = tid >> 6;
#pragma unroll
    for (int c = 0; c < C_CLS; ++c) {
#pragma unroll
        for (int off = 32; off > 0; off >>= 1) {
            isum[c] += __shfl_down(isum[c], off);
            ov[c]   += __shfl_down(ov[c],   off);
            cnt[c]  += __shfl_down(cnt[c],  off);
        }
    }

    __shared__ float sm[4][48];
    if (lane == 0) {
#pragma unroll
        for (int c = 0; c < C_CLS; ++c) {
            sm[wv][c * 3 + 0] = isum[c];
            sm[wv][c * 3 + 1] = ov[c];
            sm[wv][c * 3 + 2] = cnt[c];
        }
    }
    __syncthreads();
    if (tid < 48) {
        partial[(long)g * 48 + tid] =
            (sm[0][tid] + sm[1][tid]) + (sm[2][tid] + sm[3][tid]);
    }
}

__global__ __launch_bounds__(128)
void dice_final_kernel(const float* __restrict__ partial,
                       float*       __restrict__ out) {
    const int b    = blockIdx.x;
    const int tid  = threadIdx.x;      // 0..127 == one partial row each
    const int lane = tid & 63;
    const int wv   = tid >> 6;

    float acc[48];
    const float* row = partial + ((long)b * BLOCKS_PER_B + tid) * 48;
#pragma unroll
    for (int k = 0; k < 48; ++k) acc[k] = row[k];

#pragma unroll
    for (int k = 0; k < 48; ++k) {
#pragma unroll
        for (int off = 32; off > 0; off >>= 1)
            acc[k] += __shfl_down(acc[k], off);
    }

    __shared__ float sm[2][48];
    if (lane == 0) {
#pragma unroll
        for (int k = 0; k < 48; ++k) sm[wv][k] = acc[k];
    }
    __syncthreads();

    if (tid < C_CLS) {
        const float is = sm[0][tid * 3 + 0] + sm[1][tid * 3 + 0];
        const float o  = sm[0][tid * 3 + 1] + sm[1][tid * 3 + 1];
        const float cn = sm[0][tid * 3 + 2] + sm[1][tid * 3 + 2];
        float frac = (2.f * o + 1.f) / (is + cn + 1.f);
#pragma unroll
        for (int off = 8; off > 0; off >>= 1)
            frac += __shfl_down(frac, off, 16);
        if (tid == 0) out[b] = -frac * (1.f / (float)C_CLS);
    }
}

extern "C" void kernel_launch(void* const* d_in, const int* in_sizes, int n_in,
                              void* d_out, int out_size, void* d_ws, size_t ws_size,
                              hipStream_t stream) {
    const float* pred = (const float*)d_in[0];
    const int*   tgt  = (const int*)d_in[1];
    float*       out  = (float*)d_out;
    float*       partial = (float*)d_ws;   // 1024 * 48 * 4 B = 196608 B

    dice_partial_kernel<<<BATCH * BLOCKS_PER_B, THREADS, 0, stream>>>(pred, tgt, partial);
    dice_final_kernel<<<BATCH, 128, 0, stream>>>(partial, out);
}